// Round 1
// baseline (73.073 us; speedup 1.0000x reference)
//
#include <hip/hip_runtime.h>
#include <hip/hip_bf16.h>

// AffinityFeature: B=4, C=32, H=256, W=512 fp32.
// out[b][a][h][w] = relu( cos_sim(feature[b,:,h,w], feature[b,:,h+dh,w+dw]) )
// for the 8 non-center offsets of the 3x3 stencil (a in fixed k-order),
// 0 when the neighbor is out of bounds (reference pads AFTER normalize).

#define AF_B 4
#define AF_C 32
#define AF_H 256
#define AF_W 512
#define AF_EPS 1e-12f

__global__ __launch_bounds__(256) void affinity_kernel(const float* __restrict__ f,
                                                       float* __restrict__ out) {
    const int idx = blockIdx.x * blockDim.x + threadIdx.x;
    const int total = AF_B * AF_H * AF_W;
    if (idx >= total) return;

    const int w = idx & (AF_W - 1);
    const int h = (idx >> 9) & (AF_H - 1);   // W=512 -> 9 bits
    const int b = idx >> (9 + 8);            // H=256 -> 8 bits

    const size_t plane = (size_t)AF_H * AF_W;           // 131072
    const float* fb = f + (size_t)b * AF_C * plane;     // batch base
    const size_t pix = (size_t)h * AF_W + w;

    // ---- center vector + its squared norm ----
    float cv[AF_C];
    float ssq = 0.0f;
#pragma unroll
    for (int c = 0; c < AF_C; ++c) {
        const float v = fb[(size_t)c * plane + pix];
        cv[c] = v;
        ssq += v * v;
    }
    const float invc = 1.0f / fmaxf(sqrtf(ssq), AF_EPS);

    // ---- 8 neighbors in reference k-order: (dh,dw) row-major, skip (0,0) ----
    float* ob = out + ((size_t)b * 8) * plane + pix;

    int a = 0;
#pragma unroll
    for (int dh = -1; dh <= 1; ++dh) {
#pragma unroll
        for (int dw = -1; dw <= 1; ++dw) {
            if (dh == 0 && dw == 0) continue;
            const int hh = h + dh;
            const int ww = w + dw;
            float r = 0.0f;
            if (hh >= 0 && hh < AF_H && ww >= 0 && ww < AF_W) {
                const size_t npix = (size_t)hh * AF_W + ww;
                float dot = 0.0f, nsq = 0.0f;
#pragma unroll
                for (int c = 0; c < AF_C; ++c) {
                    const float v = fb[(size_t)c * plane + npix];
                    dot += v * cv[c];
                    nsq += v * v;
                }
                const float invn = 1.0f / fmaxf(sqrtf(nsq), AF_EPS);
                r = fmaxf(dot * invc * invn, 0.0f);
            }
            ob[(size_t)a * plane] = r;
            ++a;
        }
    }
}

extern "C" void kernel_launch(void* const* d_in, const int* in_sizes, int n_in,
                              void* d_out, int out_size, void* d_ws, size_t ws_size,
                              hipStream_t stream) {
    const float* f = (const float*)d_in[0];
    float* out = (float*)d_out;
    const int total = AF_B * AF_H * AF_W;       // 524288 threads (one per pixel)
    const int block = 256;
    const int grid = (total + block - 1) / block;   // 2048 blocks
    affinity_kernel<<<grid, block, 0, stream>>>(f, out);
}

// Round 2
// 24.883 us; speedup vs baseline: 2.9366x; 2.9366x over previous
//
#include <hip/hip_runtime.h>

// AffinityFeature, symmetric formulation.
// out[b][a][h][w] = relu( cos(feat[b,:,h,w], feat[b,:,h+dh,w+dw]) ), 0 if OOB.
// a order: 0:NW 1:N 2:NE 3:W 4:E 5:SW 6:S 7:SE.
// Symmetry: dot(p,q)=dot(q,p) -> compute only E,S,SE,SW per pixel, scatter
// the mirrored channels (W,N,NW,NE) to the neighbor pixel's location.
// Each thread: 4 consecutive pixels of one row; reads rows h and h+1 only.

#define AF_B 4
#define AF_C 32
#define AF_H 256
#define AF_W 512
#define AF_EPS 1e-12f
#define AF_PLANE ((size_t)AF_H * AF_W)

__global__ __launch_bounds__(256) void affinity_sym_kernel(const float* __restrict__ f,
                                                           float* __restrict__ out) {
    // XCD-aware swizzle: 512 blocks, 8 XCDs -> 64-block contiguous band/XCD
    const int cpx = gridDim.x >> 3;
    const int bid = ((int)blockIdx.x & 7) * cpx + ((int)blockIdx.x >> 3);

    const int G = bid * 256 + (int)threadIdx.x;   // pixel-group id (4 px each)
    const int w0 = (G & 127) << 2;                // 0,4,...,508
    const int rowIdx = G >> 7;                    // 0..1023
    const int h = rowIdx & (AF_H - 1);
    const int b = rowIdx >> 8;

    const bool vS = (h + 1) < AF_H;   // south row exists
    const bool vR = (w0 + 4) < AF_W;  // col w0+4 exists
    const bool vL = w0 > 0;           // col w0-1 exists
    const float mS = vS ? 1.0f : 0.0f;
    const float mR = vR ? 1.0f : 0.0f;
    const float mRS = mR * mS;
    const float mLS = (vL ? 1.0f : 0.0f) * mS;
    const int offR = vR ? 4 : 0;
    const int offL = vL ? -1 : 0;

    const float* pc = f + (size_t)b * AF_C * AF_PLANE + (size_t)h * AF_W + w0;
    const float* ps = pc + (vS ? AF_W : 0);

    float ssq0=0,ssq1=0,ssq2=0,ssq3=0, ssqR=0;          // center row |v|^2
    float nsq0=0,nsq1=0,nsq2=0,nsq3=0, nsqL=0,nsqR=0;   // south row |v|^2
    float dE0=0,dE1=0,dE2=0,dE3=0;
    float dS0=0,dS1=0,dS2=0,dS3=0;
    float dSE0=0,dSE1=0,dSE2=0,dSE3=0;
    float dSW0=0,dSW1=0,dSW2=0,dSW3=0;

#pragma unroll
    for (int c = 0; c < AF_C; ++c) {
        const float4 cc = *(const float4*)pc;
        const float ccR = pc[offR] * mR;
        float4 cs = *(const float4*)ps;
        const float csR = ps[offR] * mRS;
        const float csL = ps[offL] * mLS;
        cs.x *= mS; cs.y *= mS; cs.z *= mS; cs.w *= mS;
        pc += AF_PLANE; ps += AF_PLANE;

        ssq0 += cc.x*cc.x; ssq1 += cc.y*cc.y; ssq2 += cc.z*cc.z; ssq3 += cc.w*cc.w;
        ssqR += ccR*ccR;
        nsq0 += cs.x*cs.x; nsq1 += cs.y*cs.y; nsq2 += cs.z*cs.z; nsq3 += cs.w*cs.w;
        nsqL += csL*csL;   nsqR += csR*csR;
        dE0 += cc.x*cc.y;  dE1 += cc.y*cc.z;  dE2 += cc.z*cc.w;  dE3 += cc.w*ccR;
        dS0 += cc.x*cs.x;  dS1 += cc.y*cs.y;  dS2 += cc.z*cs.z;  dS3 += cc.w*cs.w;
        dSE0 += cc.x*cs.y; dSE1 += cc.y*cs.z; dSE2 += cc.z*cs.w; dSE3 += cc.w*csR;
        dSW0 += cc.x*csL;  dSW1 += cc.y*cs.x; dSW2 += cc.z*cs.y; dSW3 += cc.w*cs.z;
    }

    const float ic0 = 1.0f / fmaxf(sqrtf(ssq0), AF_EPS);
    const float ic1 = 1.0f / fmaxf(sqrtf(ssq1), AF_EPS);
    const float ic2 = 1.0f / fmaxf(sqrtf(ssq2), AF_EPS);
    const float ic3 = 1.0f / fmaxf(sqrtf(ssq3), AF_EPS);
    const float icR = 1.0f / fmaxf(sqrtf(ssqR), AF_EPS);
    const float is0 = 1.0f / fmaxf(sqrtf(nsq0), AF_EPS);
    const float is1 = 1.0f / fmaxf(sqrtf(nsq1), AF_EPS);
    const float is2 = 1.0f / fmaxf(sqrtf(nsq2), AF_EPS);
    const float is3 = 1.0f / fmaxf(sqrtf(nsq3), AF_EPS);
    const float isL = 1.0f / fmaxf(sqrtf(nsqL), AF_EPS);
    const float isR = 1.0f / fmaxf(sqrtf(nsqR), AF_EPS);

    const float E0 = fmaxf(dE0*ic0*ic1, 0.0f);
    const float E1 = fmaxf(dE1*ic1*ic2, 0.0f);
    const float E2 = fmaxf(dE2*ic2*ic3, 0.0f);
    const float E3 = fmaxf(dE3*ic3*icR, 0.0f);
    const float S0 = fmaxf(dS0*ic0*is0, 0.0f);
    const float S1 = fmaxf(dS1*ic1*is1, 0.0f);
    const float S2 = fmaxf(dS2*ic2*is2, 0.0f);
    const float S3 = fmaxf(dS3*ic3*is3, 0.0f);
    const float SE0 = fmaxf(dSE0*ic0*is1, 0.0f);
    const float SE1 = fmaxf(dSE1*ic1*is2, 0.0f);
    const float SE2 = fmaxf(dSE2*ic2*is3, 0.0f);
    const float SE3 = fmaxf(dSE3*ic3*isR, 0.0f);
    const float SW0 = fmaxf(dSW0*ic0*isL, 0.0f);
    const float SW1 = fmaxf(dSW1*ic1*is0, 0.0f);
    const float SW2 = fmaxf(dSW2*ic2*is1, 0.0f);
    const float SW3 = fmaxf(dSW3*ic3*is2, 0.0f);

    float* ob = out + (size_t)b * 8 * AF_PLANE + (size_t)h * AF_W + w0;

    // forward channels at (h, w0..w0+3), aligned float4
    *(float4*)(ob + 4*AF_PLANE) = make_float4(E0,E1,E2,E3);
    *(float4*)(ob + 6*AF_PLANE) = make_float4(S0,S1,S2,S3);
    *(float4*)(ob + 7*AF_PLANE) = make_float4(SE0,SE1,SE2,SE3);
    *(float4*)(ob + 5*AF_PLANE) = make_float4(SW0,SW1,SW2,SW3);

    // a=3 (W) at (h, w0+1..w0+4)
    float* o3 = ob + 3*AF_PLANE;
    o3[1] = E0; o3[2] = E1; o3[3] = E2;
    if (vR) o3[4] = E3;
    if (!vL) o3[0] = 0.0f;      // W of (h,0) OOB

    if (vS) {
        float* on = ob + AF_W;  // row h+1, col w0
        // a=1 (N) at (h+1, w0..w0+3)
        *(float4*)(on + 1*AF_PLANE) = make_float4(S0,S1,S2,S3);
        // a=0 (NW) at (h+1, w0+1..w0+4)
        float* o0 = on;
        o0[1] = SE0; o0[2] = SE1; o0[3] = SE2;
        if (vR) o0[4] = SE3;
        if (!vL) o0[0] = 0.0f;  // NW of (h+1,0) OOB
        // a=2 (NE) at (h+1, w0-1..w0+2)
        float* o2 = on + 2*AF_PLANE;
        if (vL) o2[-1] = SW0;
        o2[0] = SW1; o2[1] = SW2; o2[2] = SW3;
        if (!vR) o2[3] = 0.0f;  // NE of (h+1, W-1) OOB
    }

    if (h == 0) {               // N/NW/NE rows at h=0 are all OOB -> zero
        float* oz = out + (size_t)b * 8 * AF_PLANE + w0;
        const float4 z4 = make_float4(0.0f, 0.0f, 0.0f, 0.0f);
        *(float4*)(oz + 0*AF_PLANE) = z4;
        *(float4*)(oz + 1*AF_PLANE) = z4;
        *(float4*)(oz + 2*AF_PLANE) = z4;
    }
}

extern "C" void kernel_launch(void* const* d_in, const int* in_sizes, int n_in,
                              void* d_out, int out_size, void* d_ws, size_t ws_size,
                              hipStream_t stream) {
    const float* f = (const float*)d_in[0];
    float* out = (float*)d_out;
    // 4*256*512 px / 4 px/thread = 131072 threads = 512 blocks of 256
    affinity_sym_kernel<<<512, 256, 0, stream>>>(f, out);
}